// Round 4
// baseline (723.907 us; speedup 1.0000x reference)
//
#include <hip/hip_runtime.h>
#include <cstdint>
#include <cstddef>

// Problem constants (fixed by the reference: B=8, S=1024, H=512, 8 speakers, 2 layers)
#define SS 1024
#define HH 512
#define G3 1536  // 3*H

typedef _Float16 half8 __attribute__((ext_vector_type(8)));
typedef float f32x4 __attribute__((ext_vector_type(4)));

// ---- workspace layout (bytes) ----
// Rings are u32 words: (tag << 16) | f16(h).  tag = producing round + 1; memset(0)
// encodes "round -1" so round 0 consumes initial zeros with no special case.
static constexpr unsigned OFF_TLIST = 0;               // [8][8][1024] int
static constexpr unsigned OFF_LEN   = 262144;          // [64] int
static constexpr unsigned OFF_META  = 262400;          // [8] int per-speaker max chain len
static constexpr unsigned OFF_H0    = 262656;          // u32[2][64][512] = 262144 B
static constexpr unsigned OFF_H1    = OFF_H0 + 262144; // u32[2][64][512]
static constexpr unsigned WS_NEED   = OFF_H1 + 262144;

__device__ __forceinline__ half8 cvt8(const float* p) {
  float4 u = *(const float4*)p;
  float4 v = *(const float4*)(p + 4);
  half8 h;
  h[0]=(_Float16)u.x; h[1]=(_Float16)u.y; h[2]=(_Float16)u.z; h[3]=(_Float16)u.w;
  h[4]=(_Float16)v.x; h[5]=(_Float16)v.y; h[6]=(_Float16)v.z; h[7]=(_Float16)v.w;
  return h;
}

// strip low f16 from 8 tagged u32 words -> half8 (4x v_perm_b32)
__device__ __forceinline__ half8 pack8(uint4 a, uint4 b) {
  union { unsigned u[4]; half8 h; } r;
  r.u[0] = __builtin_amdgcn_perm(a.y, a.x, 0x05040100);
  r.u[1] = __builtin_amdgcn_perm(a.w, a.z, 0x05040100);
  r.u[2] = __builtin_amdgcn_perm(b.y, b.x, 0x05040100);
  r.u[3] = __builtin_amdgcn_perm(b.w, b.z, 0x05040100);
  return r.h;
}

__device__ __forceinline__ float sigm(float x) { return 1.f / (1.f + __expf(-x)); }

// ---------------- prep: build per-(sp,b) timestep lists ----------------
__global__ void prep_kernel(const int* __restrict__ spk, int* __restrict__ tlist,
                            int* __restrict__ len, int* __restrict__ meta) {
  __shared__ int slen[64];
  const int t = threadIdx.x;   // 0..63
  const int sp = t >> 3, b = t & 7;
  int cnt = 0;
  int* tl = tlist + (sp * 8 + b) * SS;
  const int4* srow = (const int4*)(spk + b * SS);
#pragma unroll 4
  for (int i = 0; i < SS / 4; ++i) {
    int4 v = srow[i];
    if (v.x == sp) tl[cnt++] = 4 * i + 0;
    if (v.y == sp) tl[cnt++] = 4 * i + 1;
    if (v.z == sp) tl[cnt++] = 4 * i + 2;
    if (v.w == sp) tl[cnt++] = 4 * i + 3;
  }
  len[t] = cnt;
  slen[t] = cnt;
  for (int i = cnt; i < SS; ++i) tl[i] = 0;  // pad so speculative reads are safe
  __syncthreads();
  if (t < 8) {
    int m = 0;
    for (int i = 0; i < 8; ++i) m = max(m, slen[t * 8 + i]);
    meta[t] = m;
  }
}

// ---------------- persistent GRU kernel ----------------
// 256 WGs: sp = wg&7, og = wg>>3; WG owns outputs j0=og*16 of BOTH layers for
// speaker sp. NO inter-WG barrier: ring words are (tag<<16)|f16, consumers poll
// the data itself. Max skew between WGs of a speaker is 1 round (each round's
// stage consumes all columns = all producers), which makes the 2-slot ring safe.
// Inactive chains keep re-publishing their last h each round so polls terminate.
__launch_bounds__(256, 1)
__global__ void gru_main(const float* __restrict__ x,
                         const float* __restrict__ Wi, const float* __restrict__ Wh,
                         const float* __restrict__ bi, const float* __restrict__ bh,
                         const int* __restrict__ tlist, const int* __restrict__ len,
                         const int* __restrict__ meta,
                         unsigned* __restrict__ h0ring, unsigned* __restrict__ h1ring,
                         float* __restrict__ out) {
  const int wg = blockIdx.x;      // 0..255
  const int sp = wg & 7;          // speaker grouped by XCD round-robin
  const int og = wg >> 3;         // 0..31
  const int j0 = og * 16;
  const int tid = threadIdx.x;
  const int w  = tid >> 6;        // wave 0..3 (owns K-quarter)
  const int l  = tid & 63;
  const int lr = l & 15;          // A-row (batch) / B-col (weight row in tile)
  const int lg = l >> 4;          // k sub-group
  const int b8 = lr & 7;          // batch row (rows 8-15 duplicate 0-7)

  // accbuf[w][slab][n*20+m]: slab 0..2 = x-GEMM gates, 3..11 = h-GEMM gates.
  // pitch 20 -> f32x4 stores quad-distinct per 8-lane group (conflict-free).
  __shared__ float accbuf[4][12][320];
  // raw tagged words; pitch 516 -> b128 reads bank-bijective over (b8,lg).
  __shared__ unsigned hstage[2][8][516];

  // ---- weight preload: fp32 global -> f16 register fragments (done once) ----
  const size_t WMAT = (size_t)G3 * HH;
  const float* pWi0 = Wi + (size_t)(sp * 2 + 0) * WMAT;
  const float* pWh0 = Wh + (size_t)(sp * 2 + 0) * WMAT;
  const float* pWi1 = Wi + (size_t)(sp * 2 + 1) * WMAT;
  const float* pWh1 = Wh + (size_t)(sp * 2 + 1) * WMAT;

  half8 bwi0[3][4], bwh0[3][4], bwi1[3][4], bwh1[3][4];
#pragma unroll
  for (int T = 0; T < 3; ++T) {
#pragma unroll
    for (int q = 0; q < 4; ++q) {
      const size_t row = (size_t)(T * HH + j0 + lr);
      const int k0 = lg * 8 + (w * 4 + q) * 32;
      bwi0[T][q] = cvt8(pWi0 + row * HH + k0);
      bwh0[T][q] = cvt8(pWh0 + row * HH + k0);
      bwi1[T][q] = cvt8(pWi1 + row * HH + k0);
      bwh1[T][q] = cvt8(pWh1 + row * HH + k0);
    }
  }

  // ---- gate-thread metadata: threads 0..127 = layer0, 128..255 = layer1 ----
  const bool isA = tid < 128;
  const int u_ = isA ? tid : (tid - 128);
  const int gb = u_ >> 4;     // batch
  const int gj = u_ & 15;     // output within group
  const int Lb = len[sp * 8 + gb];
  const int* tlB = tlist + (sp * 8 + gb) * SS;
  float bAi[3], bAh[3], bBi[3], bBh[3];
#pragma unroll
  for (int g = 0; g < 3; ++g) {
    const int n = g * HH + j0 + gj;
    bAi[g] = bi[(sp * 2 + 0) * G3 + n];
    bAh[g] = bh[(sp * 2 + 0) * G3 + n];
    bBi[g] = bi[(sp * 2 + 1) * G3 + n];
    bBh[g] = bh[(sp * 2 + 1) * G3 + n];
  }

  // per-lane x-gather metadata (A row b8 supplies batch b8)
  const int* tlX = tlist + (sp * 8 + b8) * SS;
  const float* xrow_base = x + (size_t)b8 * SS * HH;

  const int maxlen = meta[sp];

  float h0prev = 0.f, h1prev = 0.f;   // recurrent state for this thread's (gb, j0+gj)

  // ---- prologue: x-GEMM (Wi0 * x_0) into accbuf[w][0..2] ----
  {
    const int tx = tlX[0];
    const float* xs = xrow_base + (size_t)tx * HH;
    half8 xf[4];
    f32x4 a0[3];
#pragma unroll
    for (int T = 0; T < 3; ++T)
#pragma unroll
      for (int e = 0; e < 4; ++e) a0[T][e] = 0.f;
#pragma unroll
    for (int q = 0; q < 4; ++q) xf[q] = cvt8(xs + lg * 8 + (w * 4 + q) * 32);
#pragma unroll
    for (int T = 0; T < 3; ++T)
#pragma unroll
      for (int q = 0; q < 4; ++q)
        a0[T] = __builtin_amdgcn_mfma_f32_16x16x32_f16(xf[q], bwi0[T][q], a0[T], 0, 0, 0);
#pragma unroll
    for (int T = 0; T < 3; ++T)
      *(f32x4*)&accbuf[w][T][lr * 20 + lg * 4] = a0[T];
  }

  for (int r = 0; r <= maxlen; ++r) {
    // ---- A: stage-poll both rings (expect tag r on every word) ----
    {
      const unsigned exp = (unsigned)r;
      const unsigned* src0 = h0ring + ((size_t)(((r - 1) & 1) * 64 + sp * 8)) * HH;
      const unsigned* src1 = h1ring + ((size_t)((r & 1) * 64 + sp * 8)) * HH;
      unsigned v0[16], v1[16];
#pragma unroll
      for (int j = 0; j < 16; ++j) {
        v0[j] = __hip_atomic_load(src0 + j * 256 + tid, __ATOMIC_RELAXED, __HIP_MEMORY_SCOPE_AGENT);
        v1[j] = __hip_atomic_load(src1 + j * 256 + tid, __ATOMIC_RELAXED, __HIP_MEMORY_SCOPE_AGENT);
      }
      unsigned iters = 0;
      while (true) {
        unsigned bad = 0;
#pragma unroll
        for (int j = 0; j < 16; ++j) {
          bad |= (v0[j] >> 16) ^ exp;
          bad |= (v1[j] >> 16) ^ exp;
        }
        if (!bad) break;
        __builtin_amdgcn_s_sleep(1);
        if (++iters > 100000000u) break;   // safety against pathological hang
#pragma unroll
        for (int j = 0; j < 16; ++j) {
          if ((v0[j] >> 16) != exp)
            v0[j] = __hip_atomic_load(src0 + j * 256 + tid, __ATOMIC_RELAXED, __HIP_MEMORY_SCOPE_AGENT);
          if ((v1[j] >> 16) != exp)
            v1[j] = __hip_atomic_load(src1 + j * 256 + tid, __ATOMIC_RELAXED, __HIP_MEMORY_SCOPE_AGENT);
        }
      }
#pragma unroll
      for (int j = 0; j < 16; ++j) {
        const int e = j * 256 + tid;
        hstage[0][e >> 9][e & 511] = v0[j];
        hstage[1][e >> 9][e & 511] = v1[j];
      }
    }
    __syncthreads();   // hstage ready; accbuf[0..2] (x-GEMM) ready

    // ---- C: A-frags from LDS (strip tags) + 36 MFMA (Wh0*h0, Wi1*h0, Wh1*h1) ----
    half8 hA0[4], hA1[4];
#pragma unroll
    for (int q = 0; q < 4; ++q) {
      const int k0 = lg * 8 + (w * 4 + q) * 32;
      uint4 a0 = *(const uint4*)&hstage[0][b8][k0];
      uint4 a1 = *(const uint4*)&hstage[0][b8][k0 + 4];
      uint4 c0 = *(const uint4*)&hstage[1][b8][k0];
      uint4 c1 = *(const uint4*)&hstage[1][b8][k0 + 4];
      hA0[q] = pack8(a0, a1);
      hA1[q] = pack8(c0, c1);
    }
    f32x4 acc[3][3];
#pragma unroll
    for (int Gm = 0; Gm < 3; ++Gm)
#pragma unroll
      for (int T = 0; T < 3; ++T)
#pragma unroll
        for (int e = 0; e < 4; ++e) acc[Gm][T][e] = 0.f;
#pragma unroll
    for (int T = 0; T < 3; ++T) {
#pragma unroll
      for (int q = 0; q < 4; ++q) {
        acc[0][T] = __builtin_amdgcn_mfma_f32_16x16x32_f16(hA0[q], bwh0[T][q], acc[0][T], 0, 0, 0);
        acc[1][T] = __builtin_amdgcn_mfma_f32_16x16x32_f16(hA0[q], bwi1[T][q], acc[1][T], 0, 0, 0);
        acc[2][T] = __builtin_amdgcn_mfma_f32_16x16x32_f16(hA1[q], bwh1[T][q], acc[2][T], 0, 0, 0);
      }
    }
#pragma unroll
    for (int Gm = 0; Gm < 3; ++Gm)
#pragma unroll
      for (int T = 0; T < 3; ++T)
        *(f32x4*)&accbuf[w][3 + Gm * 3 + T][lr * 20 + lg * 4] = acc[Gm][T];
    __syncthreads();   // accbuf complete

    // ---- E: gates; ALWAYS publish tagged word (even for finished chains) ----
    const int ci = gj * 20 + gb;
    const unsigned tagw = ((unsigned)(r + 1)) << 16;
    if (isA) {
      if (r < Lb) {
        float giv[3], ghv[3];
#pragma unroll
        for (int g = 0; g < 3; ++g) {
          giv[g] = accbuf[0][g][ci] + accbuf[1][g][ci] + accbuf[2][g][ci] + accbuf[3][g][ci] + bAi[g];
          ghv[g] = accbuf[0][3 + g][ci] + accbuf[1][3 + g][ci] + accbuf[2][3 + g][ci] + accbuf[3][3 + g][ci] + bAh[g];
        }
        const float rr = sigm(giv[0] + ghv[0]);
        const float zz = sigm(giv[1] + ghv[1]);
        const float nn = tanhf(giv[2] + rr * ghv[2]);
        h0prev = (1.f - zz) * nn + zz * h0prev;
      }
      union { _Float16 hf; unsigned short us; } cv; cv.hf = (_Float16)h0prev;
      __hip_atomic_store(&h0ring[((size_t)((r & 1) * 64 + sp * 8 + gb)) * HH + j0 + gj],
                         tagw | (unsigned)cv.us, __ATOMIC_RELAXED, __HIP_MEMORY_SCOPE_AGENT);
    } else {
      if ((r >= 1) && (r <= Lb)) {
        float giv[3], ghv[3];
#pragma unroll
        for (int g = 0; g < 3; ++g) {
          giv[g] = accbuf[0][6 + g][ci] + accbuf[1][6 + g][ci] + accbuf[2][6 + g][ci] + accbuf[3][6 + g][ci] + bBi[g];
          ghv[g] = accbuf[0][9 + g][ci] + accbuf[1][9 + g][ci] + accbuf[2][9 + g][ci] + accbuf[3][9 + g][ci] + bBh[g];
        }
        const float rr = sigm(giv[0] + ghv[0]);
        const float zz = sigm(giv[1] + ghv[1]);
        const float nn = tanhf(giv[2] + rr * ghv[2]);
        h1prev = (1.f - zz) * nn + zz * h1prev;
        const int tcur = tlB[(r - 1) & (SS - 1)];
        out[((size_t)(gb * SS + tcur)) * HH + j0 + gj] = h1prev;
      }
      union { _Float16 hf; unsigned short us; } cv; cv.hf = (_Float16)h1prev;
      __hip_atomic_store(&h1ring[((size_t)(((r - 1) & 1) * 64 + sp * 8 + gb)) * HH + j0 + gj],
                         tagw | (unsigned)cv.us, __ATOMIC_RELAXED, __HIP_MEMORY_SCOPE_AGENT);
    }

    __syncthreads();   // gates done reading accbuf[0..2] before x-GEMM overwrites

    // ---- G: x-GEMM (Wi0 * x_{r+1}) into accbuf[w][0..2]; overlaps others' polling ----
    {
      const int tx = tlX[(r + 1) & (SS - 1)];
      const float* xs = xrow_base + (size_t)tx * HH;
      half8 xf[4];
      f32x4 a0[3];
#pragma unroll
      for (int T = 0; T < 3; ++T)
#pragma unroll
        for (int e = 0; e < 4; ++e) a0[T][e] = 0.f;
#pragma unroll
      for (int q = 0; q < 4; ++q) xf[q] = cvt8(xs + lg * 8 + (w * 4 + q) * 32);
#pragma unroll
      for (int T = 0; T < 3; ++T)
#pragma unroll
        for (int q = 0; q < 4; ++q)
          a0[T] = __builtin_amdgcn_mfma_f32_16x16x32_f16(xf[q], bwi0[T][q], a0[T], 0, 0, 0);
#pragma unroll
      for (int T = 0; T < 3; ++T)
        *(f32x4*)&accbuf[w][T][lr * 20 + lg * 4] = a0[T];
    }
    // no trailing barrier needed: next round's hstage writes and this accbuf write
    // are both separated from their readers by the next round's two syncthreads.
  }
}

extern "C" void kernel_launch(void* const* d_in, const int* in_sizes, int n_in,
                              void* d_out, int out_size, void* d_ws, size_t ws_size,
                              hipStream_t stream) {
  const float* x   = (const float*)d_in[0];
  const int*   spk = (const int*)d_in[1];
  const float* Wi  = (const float*)d_in[2];
  const float* Wh  = (const float*)d_in[3];
  const float* bi  = (const float*)d_in[4];
  const float* bh  = (const float*)d_in[5];
  float* out = (float*)d_out;
  char* ws = (char*)d_ws;

  int*      tlist = (int*)(ws + OFF_TLIST);
  int*      len   = (int*)(ws + OFF_LEN);
  int*      meta  = (int*)(ws + OFF_META);
  unsigned* h0r   = (unsigned*)(ws + OFF_H0);
  unsigned* h1r   = (unsigned*)(ws + OFF_H1);

  (void)in_sizes; (void)n_in; (void)out_size; (void)ws_size;

  // zero rings (tags -> "round -1"); re-done every launch, graph-capture safe
  hipMemsetAsync(ws + OFF_H0, 0, WS_NEED - OFF_H0, stream);
  prep_kernel<<<1, 64, 0, stream>>>(spk, tlist, len, meta);
  gru_main<<<256, 256, 0, stream>>>(x, Wi, Wh, bi, bh, tlist, len, meta, h0r, h1r, out);
}